// Round 11
// baseline (329.380 us; speedup 1.0000x reference)
//
#include <hip/hip_runtime.h>
#include <hip/hip_bf16.h>
#include <stdint.h>

// Self-attention: out = softmax((xWq+bq)(xWk+bk)^T / 32) (xWv+bv) Wo + bo
// B=4, C=2048, D_IN=D_H=D_OUT=1024. fp32 in/out; bf16 MFMA internally.
// R10: split-softmax fusion. scores8 epilogue emits per-row-slice max/sumexp
//      stats (from bf16-ROUNDED values, bit-consistent with S); PV combines
//      stats and applies exp inline while reg-staging A. softmax pass gone.
//      Pipeline: prep -> qkv(2ph) -> scores8s(8ph+stats) -> vtrans ->
//                pv_sm(2ph+exp) -> out(2ph).

typedef unsigned short u16;
typedef __attribute__((ext_vector_type(8))) short bf16x8;   // 8 bf16 = 4 VGPR
typedef __attribute__((ext_vector_type(8))) unsigned short u16x8;
typedef __attribute__((ext_vector_type(4))) float f32x4;    // MFMA 16x16 acc

#define BATCH 4
#define CSEQ  2048
#define DIM   1024
#define NQKV  3072
#define LOG2E 1.44269504f

__device__ __forceinline__ u16 f2bf(float f) {
  union { float f; uint32_t u; } v; v.f = f;
  uint32_t r = (v.u + 0x7fffu + ((v.u >> 16) & 1u)) >> 16;  // RNE
  return (u16)r;
}
__device__ __forceinline__ float bf2f(u16 h) {
  union { uint32_t u; float f; } v; v.u = (uint32_t)h << 16;
  return v.f;
}

__device__ __forceinline__ void gload_lds16(const void* g, void* lds) {
  // async global->LDS, 16B per lane; LDS dest = wave-uniform base + lane*16
  __builtin_amdgcn_global_load_lds(
      (const __attribute__((address_space(1))) unsigned int*)g,
      (__attribute__((address_space(3))) unsigned int*)lds, 16, 0, 0);
}

// ---------------------------------------------------------------------------
// prep: blocks [0,8192): cast x->bf16 (+bqkv concat in first 3072 threads);
//       blocks [8192,12288): transpose+cast Wq/Wk/Wv/Wo (z=0..3; z==0 folds
//       the 1/sqrt(D_H)=2^-5 score scale, exact in bf16).
__global__ __launch_bounds__(256) void prep(
    const float4* __restrict__ x4, ushort4* __restrict__ xbf,
    const float* __restrict__ Wq, const float* __restrict__ Wk,
    const float* __restrict__ Wv, const float* __restrict__ Wo,
    u16* __restrict__ Wqkv_t, u16* __restrict__ Wo_t,
    const float* __restrict__ bq, const float* __restrict__ bk,
    const float* __restrict__ bv, float* __restrict__ bqkv) {
  const int bid = blockIdx.x, tid = threadIdx.x;
  if (bid < 8192) {  // ---- cast + bias
    int i = bid * 256 + tid;
    float4 v = x4[i];
    ushort4 o;
    o.x = f2bf(v.x); o.y = f2bf(v.y); o.z = f2bf(v.z); o.w = f2bf(v.w);
    xbf[i] = o;
    if (i < NQKV) {
      float b = (i < 1024) ? bq[i] * 0.03125f
                           : (i < 2048) ? bk[i - 1024] : bv[i - 2048];
      bqkv[i] = b;
    }
  } else {  // ---- weight transpose (1024 blocks per matrix)
    int b = bid - 8192;
    int z = b >> 10;
    int r = b & 1023;
    int bx = (r & 31) * 32, by = (r >> 5) * 32;
    int tx = tid & 31, ty = tid >> 5;  // 32 x 8
    const float* W = (z == 0) ? Wq : (z == 1) ? Wk : (z == 2) ? Wv : Wo;
    u16* dst = (z == 3) ? Wo_t : Wqkv_t + (size_t)z * DIM * DIM;
    const float sc = (z == 0) ? 0.03125f : 1.0f;
    __shared__ float t[32][33];
#pragma unroll
    for (int i = 0; i < 4; ++i)
      t[ty + i * 8][tx] = W[(size_t)(by + ty + i * 8) * DIM + bx + tx];
    __syncthreads();
#pragma unroll
    for (int i = 0; i < 4; ++i)
      dst[(size_t)(bx + ty + i * 8) * DIM + by + tx] =
          f2bf(t[tx][ty + i * 8] * sc);
  }
}

// vtrans: V (cols 2048..3071 of QKV) -> Vt[b][h][c]
__global__ __launch_bounds__(256) void vtrans(
    const u16* __restrict__ QKV, u16* __restrict__ Vt) {
  __shared__ u16 t[32][34];
  const int tid = threadIdx.x;
  int b = blockIdx.x;
  int z = b >> 11;
  int r = b & 2047;
  int bx = (r & 31) * 32;   // h-tile base
  int by = (r >> 5) * 32;   // c-tile base
  int tx = tid & 31, ty = tid >> 5;
  const u16* src = QKV + 2048 + (size_t)z * CSEQ * NQKV;
  u16* dst = Vt + (size_t)z * DIM * CSEQ;
#pragma unroll
  for (int i = 0; i < 4; ++i)
    t[ty + i * 8][tx] = src[(size_t)(by + ty + i * 8) * NQKV + bx + tx];
  __syncthreads();
#pragma unroll
  for (int i = 0; i < 4; ++i)
    dst[(size_t)(bx + ty + i * 8) * CSEQ + by + tx] = t[tx][ty + i * 8];
}

// ---------------------------------------------------------------------------
// 2-phase 128x128 GEMM (verified R3): C = A[M][K] * Bt[N][K]^T (+bias)(*scale)
template <bool OUT_BF16, bool HAS_BIAS>
__device__ __forceinline__ void gemm_body(
    const u16* __restrict__ A, const u16* __restrict__ Bt, void* __restrict__ C,
    const float* __restrict__ bias, int K, int lda, int ldb, int ldc,
    size_t sA, size_t sB, size_t sC, float scale) {
  __shared__ __align__(16) u16 As[2][128 * 64];
  __shared__ __align__(16) u16 Bs[2][128 * 64];

  const int tid = threadIdx.x;
  const int lane = tid & 63;
  const int w = tid >> 6;
  const int wm = w >> 1, wn = w & 1;
  const int bz = blockIdx.z;
  const int m0 = blockIdx.y * 128;
  const int n0 = blockIdx.x * 128;

  A += (size_t)bz * sA;
  Bt += (size_t)bz * sB;

  f32x4 acc[4][4] = {};

  auto stage = [&](int buf, int k0) {
#pragma unroll
    for (int r = 0; r < 4; ++r) {
      int flat = r * 256 + tid;
      int row = flat >> 3;
      int s = (flat & 7) ^ (row & 7);  // inverse-swizzled source (rule #21)
      const u16* ga = A + (size_t)(m0 + row) * lda + (k0 + s * 8);
      const u16* gb = Bt + (size_t)(n0 + row) * ldb + (k0 + s * 8);
      int ubase = (r * 256 + (tid & ~63)) * 16;
      gload_lds16(ga, (char*)&As[buf][0] + ubase);
      gload_lds16(gb, (char*)&Bs[buf][0] + ubase);
    }
  };

  auto compute = [&](int buf) {
#pragma unroll
    for (int kk = 0; kk < 2; ++kk) {
      bf16x8 a[4], b[4];
#pragma unroll
      for (int i = 0; i < 4; ++i) {
        int rowa = wm * 64 + i * 16 + (lane & 15);
        int sl = kk * 4 + (lane >> 4);
        a[i] = *(const bf16x8*)&As[buf][rowa * 64 + (sl ^ (rowa & 7)) * 8];
        int rowb = wn * 64 + i * 16 + (lane & 15);
        b[i] = *(const bf16x8*)&Bs[buf][rowb * 64 + (sl ^ (rowb & 7)) * 8];
      }
#pragma unroll
      for (int mi = 0; mi < 4; ++mi)
#pragma unroll
        for (int ni = 0; ni < 4; ++ni)
          acc[mi][ni] = __builtin_amdgcn_mfma_f32_16x16x32_bf16(
              a[mi], b[ni], acc[mi][ni], 0, 0, 0);
    }
  };

  const int nk = K >> 6;
  stage(0, 0);
  __syncthreads();
  int buf = 0;
  for (int kt = 0; kt < nk - 1; ++kt) {
    stage(buf ^ 1, (kt + 1) << 6);
    compute(buf);
    __syncthreads();
    buf ^= 1;
  }
  compute(buf);

#pragma unroll
  for (int ni = 0; ni < 4; ++ni) {
    int col = n0 + wn * 64 + ni * 16 + (lane & 15);
    float bv = 0.f;
    if constexpr (HAS_BIAS) bv = bias[col];
#pragma unroll
    for (int mi = 0; mi < 4; ++mi) {
      int row0 = m0 + wm * 64 + mi * 16 + (lane >> 4) * 4;
#pragma unroll
      for (int j = 0; j < 4; ++j) {
        float o = (acc[mi][ni][j] + bv) * scale;
        size_t off = (size_t)bz * sC + (size_t)(row0 + j) * ldc + col;
        if constexpr (OUT_BF16)
          ((u16*)C)[off] = f2bf(o);
        else
          ((float*)C)[off] = o;
      }
    }
  }
}

__global__ __launch_bounds__(256, 2) void gemm_qkv(
    const u16* A, const u16* Bt, void* C, const float* bias, int K, int lda,
    int ldb, int ldc, size_t sA, size_t sB, size_t sC, float scale) {
  gemm_body<true, true>(A, Bt, C, bias, K, lda, ldb, ldc, sA, sB, sC, scale);
}
__global__ __launch_bounds__(256, 2) void gemm_out(
    const u16* A, const u16* Bt, void* C, const float* bias, int K, int lda,
    int ldb, int ldc, size_t sA, size_t sB, size_t sC, float scale) {
  gemm_body<false, true>(A, Bt, C, bias, K, lda, ldb, ldc, sA, sB, sC, scale);
}

// ---------------------------------------------------------------------------
// 8-phase 256x256 scores GEMM + per-row-slice softmax stats.
// Stats computed from bf16-ROUNDED S values -> bit-consistent with what
// pv_sm re-reads. pmax/psum layout: [b][32 col-slices][2048 rows] f32.
__global__ __launch_bounds__(512, 2) void gemm8_scores(
    const u16* __restrict__ A, const u16* __restrict__ Bt, u16* __restrict__ C,
    float* __restrict__ pmax, float* __restrict__ psum,
    int K, int lda, int ldb, int ldc, size_t sA, size_t sB, size_t sC) {
  __shared__ __align__(16) u16 As[2][2][128 * 64];
  __shared__ __align__(16) u16 Bs[2][2][128 * 64];

  const int tid = threadIdx.x;   // 0..511
  const int lane = tid & 63;
  const int w = tid >> 6;        // 0..7
  const int wm = w >> 2;         // 0..1  M half
  const int wn = w & 3;          // 0..3  N quarter
  const int bz = blockIdx.z;
  const int m0 = blockIdx.y * 256;
  const int n0 = blockIdx.x * 256;
  A += (size_t)bz * sA;
  Bt += (size_t)bz * sB;

  f32x4 acc[8][4] = {};

  auto stage_half = [&](u16* ldsHalf, const u16* g, int row0, int ld, int k0) {
#pragma unroll
    for (int r = 0; r < 2; ++r) {
      int flat = r * 512 + tid;
      int row = flat >> 3;
      int s = (flat & 7) ^ (row & 7);  // inverse swizzle on source (rule #21)
      const u16* ga = g + (size_t)(row0 + row) * ld + (k0 + s * 8);
      int ubase = (r * 512 + (tid & ~63)) * 16;
      gload_lds16(ga, (char*)ldsHalf + ubase);
    }
  };

  const int nk = K >> 6;
  stage_half(As[0][0], A, m0, lda, 0);
  stage_half(As[0][1], A, m0 + 128, lda, 0);
  stage_half(Bs[0][0], Bt, n0, ldb, 0);
  stage_half(Bs[0][1], Bt, n0 + 128, ldb, 0);
  stage_half(Bs[1][0], Bt, n0, ldb, 64);
  stage_half(As[1][0], A, m0, lda, 64);
  asm volatile("s_waitcnt vmcnt(4)" ::: "memory");
  asm volatile("s_barrier" ::: "memory");

  for (int t = 0; t < nk; ++t) {
    const int p = t & 1;
    const u16* Abuf = &As[p][wm][0];
    const u16* Bbuf = &Bs[p][wn >> 1][0];
    const int bR0 = (wn & 1) * 64;
    const int rl = lane & 15;
    const int su = lane >> 4;
    bf16x8 a[4][2], b[4][2];

    auto rdA = [&](int fi, int fbase) {
#pragma unroll
      for (int ks = 0; ks < 2; ++ks) {
        int row = (fbase + fi) * 16 + rl;
        int sl = ks * 4 + su;
        a[fi][ks] = *(const bf16x8*)&Abuf[row * 64 + ((sl ^ (row & 7))) * 8];
      }
    };
    auto rdB = [&](int nf) {
#pragma unroll
      for (int ks = 0; ks < 2; ++ks) {
        int row = bR0 + nf * 16 + rl;
        int sl = ks * 4 + su;
        b[nf][ks] = *(const bf16x8*)&Bbuf[row * 64 + ((sl ^ (row & 7))) * 8];
      }
    };
    auto quad = [&](int mbase, int nbase) {
      __builtin_amdgcn_s_setprio(1);
#pragma unroll
      for (int fi = 0; fi < 4; ++fi)
#pragma unroll
        for (int nf = 0; nf < 2; ++nf)
#pragma unroll
          for (int ks = 0; ks < 2; ++ks)
            acc[mbase + fi][nbase + nf] = __builtin_amdgcn_mfma_f32_16x16x32_bf16(
                a[fi][ks], b[nbase + nf][ks], acc[mbase + fi][nbase + nf], 0, 0, 0);
      __builtin_amdgcn_s_setprio(0);
    };
    auto barrier_in = [&]() {
      asm volatile("s_barrier" ::: "memory");
      asm volatile("s_waitcnt lgkmcnt(0)" ::: "memory");
      __builtin_amdgcn_sched_barrier(0);  // rule #18
    };

    rdA(0, 0); rdA(1, 0); rdA(2, 0); rdA(3, 0);
    rdB(0); rdB(1);
    if (t + 1 < nk) stage_half(Bs[1 - p][1], Bt, n0 + 128, ldb, (t + 1) * 64);
    barrier_in();
    quad(0, 0);
    asm volatile("s_barrier" ::: "memory");

    rdB(2); rdB(3);
    if (t + 1 < nk) stage_half(As[1 - p][1], A, m0 + 128, lda, (t + 1) * 64);
    barrier_in();
    quad(0, 2);
    asm volatile("s_barrier" ::: "memory");

    rdA(0, 4); rdA(1, 4); rdA(2, 4); rdA(3, 4);
    if (t + 2 < nk) stage_half(Bs[p][0], Bt, n0, ldb, (t + 2) * 64);
    barrier_in();
    quad(4, 2);
    asm volatile("s_barrier" ::: "memory");

    if (t + 2 < nk) stage_half(As[p][0], A, m0, lda, (t + 2) * 64);
    barrier_in();
    quad(4, 0);
    if (t + 2 < nk)
      asm volatile("s_waitcnt vmcnt(4)" ::: "memory");
    else if (t + 1 < nk)
      asm volatile("s_waitcnt vmcnt(0)" ::: "memory");
    asm volatile("s_barrier" ::: "memory");
  }

  // epilogue: C write + per-row stats over this wave's 64-col slice.
  // slice id cb = blockIdx.x*4 + wn (32 slices of 64 cols per row).
  const size_t cbase = (size_t)bz * sC;
  float* pm = pmax + ((size_t)bz * 32 + (blockIdx.x * 4 + wn)) * CSEQ;
  float* ps = psum + ((size_t)bz * 32 + (blockIdx.x * 4 + wn)) * CSEQ;
  const int su = lane >> 4;
#pragma unroll
  for (int fi = 0; fi < 8; ++fi) {
#pragma unroll
    for (int j = 0; j < 4; ++j) {
      const int row = wm * 128 + fi * 16 + su * 4 + j;  // 0..255 in tile
      float rv[4];
#pragma unroll
      for (int nf = 0; nf < 4; ++nf) {
        u16 c = f2bf(acc[fi][nf][j]);
        C[cbase + (size_t)(m0 + row) * ldc +
          (n0 + wn * 64 + nf * 16 + (lane & 15))] = c;
        rv[nf] = bf2f(c);  // ROUNDED value -> stats consistent with S
      }
      float m = fmaxf(fmaxf(rv[0], rv[1]), fmaxf(rv[2], rv[3]));
#pragma unroll
      for (int mk = 1; mk < 16; mk <<= 1) m = fmaxf(m, __shfl_xor(m, mk));
      float s = exp2f((rv[0] - m) * LOG2E) + exp2f((rv[1] - m) * LOG2E) +
                exp2f((rv[2] - m) * LOG2E) + exp2f((rv[3] - m) * LOG2E);
#pragma unroll
      for (int mk = 1; mk < 16; mk <<= 1) s += __shfl_xor(s, mk);
      if ((lane & 15) == 0) {
        pm[m0 + row] = m;
        ps[m0 + row] = s;
      }
    }
  }
}

// ---------------------------------------------------------------------------
// PV with fused softmax: attn[b] = softmax(S[b]) * Vt[b]^T.
// 2-phase 128x128; A (=S) is reg-staged with p = exp2((s-m)*log2e)*inv
// applied inline; B (=Vt) stays gload_lds16. Row stats combined from the
// 32 per-slice partials emitted by gemm8_scores.
__global__ __launch_bounds__(256, 2) void gemm_pv_sm(
    const u16* __restrict__ S, const u16* __restrict__ Vt, u16* __restrict__ C,
    const float* __restrict__ pmax, const float* __restrict__ psum) {
  __shared__ __align__(16) u16 As[2][128 * 64];
  __shared__ __align__(16) u16 Bs[2][128 * 64];
  __shared__ float mrow[128], irow[128];

  const int tid = threadIdx.x;
  const int lane = tid & 63;
  const int w = tid >> 6;
  const int wm = w >> 1, wn = w & 1;
  const int bz = blockIdx.z;
  const int m0 = blockIdx.y * 128;
  const int n0 = blockIdx.x * 128;
  const u16* A = S + (size_t)bz * CSEQ * CSEQ;
  const u16* B = Vt + (size_t)bz * (size_t)DIM * CSEQ;

  // ---- combine per-slice stats -> m, 1/sum per row (threads 0..127)
  if (tid < 128) {
    const float* pm = pmax + (size_t)bz * 32 * CSEQ + (m0 + tid);
    const float* ps = psum + (size_t)bz * 32 * CSEQ + (m0 + tid);
    float m = -3.4e38f;
#pragma unroll 8
    for (int cb = 0; cb < 32; ++cb) m = fmaxf(m, pm[(size_t)cb * CSEQ]);
    float s = 0.f;
#pragma unroll 8
    for (int cb = 0; cb < 32; ++cb)
      s += ps[(size_t)cb * CSEQ] * exp2f((pm[(size_t)cb * CSEQ] - m) * LOG2E);
    mrow[tid] = m;
    irow[tid] = 1.0f / s;
  }
  __syncthreads();
  // each thread's 4 staged A-rows are fixed: row = r*32 + (tid>>3)
  float mreg[4], ireg[4];
#pragma unroll
  for (int r = 0; r < 4; ++r) {
    int rr = r * 32 + (tid >> 3);
    mreg[r] = mrow[rr];
    ireg[r] = irow[rr];
  }

  f32x4 acc[4][4] = {};

  auto stageA = [&](int buf, int k0) {  // reg-staged, exp fused
#pragma unroll
    for (int r = 0; r < 4; ++r) {
      int flat = r * 256 + tid;
      int row = flat >> 3;
      int sl = (flat & 7) ^ (row & 7);
      u16x8 sv = *(const u16x8*)(A + (size_t)(m0 + row) * CSEQ + k0 + sl * 8);
      u16x8 o;
#pragma unroll
      for (int i = 0; i < 8; ++i)
        o[i] = f2bf(exp2f((bf2f(sv[i]) - mreg[r]) * LOG2E) * ireg[r]);
      *(u16x8*)((char*)&As[buf][0] + flat * 16) = o;
    }
  };
  auto stageB = [&](int buf, int k0) {
#pragma unroll
    for (int r = 0; r < 4; ++r) {
      int flat = r * 256 + tid;
      int row = flat >> 3;
      int sl = (flat & 7) ^ (row & 7);
      gload_lds16(B + (size_t)(n0 + row) * CSEQ + k0 + sl * 8,
                  (char*)&Bs[buf][0] + (r * 256 + (tid & ~63)) * 16);
    }
  };
  auto compute = [&](int buf) {
#pragma unroll
    for (int kk = 0; kk < 2; ++kk) {
      bf16x8 a[4], b[4];
#pragma unroll
      for (int i = 0; i < 4; ++i) {
        int rowa = wm * 64 + i * 16 + (lane & 15);
        int sl = kk * 4 + (lane >> 4);
        a[i] = *(const bf16x8*)&As[buf][rowa * 64 + (sl ^ (rowa & 7)) * 8];
        int rowb = wn * 64 + i * 16 + (lane & 15);
        b[i] = *(const bf16x8*)&Bs[buf][rowb * 64 + (sl ^ (rowb & 7)) * 8];
      }
#pragma unroll
      for (int mi = 0; mi < 4; ++mi)
#pragma unroll
        for (int ni = 0; ni < 4; ++ni)
          acc[mi][ni] = __builtin_amdgcn_mfma_f32_16x16x32_bf16(
              a[mi], b[ni], acc[mi][ni], 0, 0, 0);
    }
  };

  const int nk = CSEQ >> 6;  // 32
  stageA(0, 0);
  stageB(0, 0);
  __syncthreads();
  int buf = 0;
  for (int kt = 0; kt < nk - 1; ++kt) {
    stageA(buf ^ 1, (kt + 1) << 6);
    stageB(buf ^ 1, (kt + 1) << 6);
    compute(buf);
    __syncthreads();
    buf ^= 1;
  }
  compute(buf);

  u16* Cb = C + (size_t)bz * CSEQ * DIM;
#pragma unroll
  for (int ni = 0; ni < 4; ++ni) {
    int col = n0 + wn * 64 + ni * 16 + (lane & 15);
#pragma unroll
    for (int mi = 0; mi < 4; ++mi) {
      int row0 = m0 + wm * 64 + mi * 16 + (lane >> 4) * 4;
#pragma unroll
      for (int j = 0; j < 4; ++j)
        Cb[(size_t)(row0 + j) * DIM + col] = f2bf(acc[mi][ni][j]);
    }
  }
}

// ---------------------------------------------------------------------------
extern "C" void kernel_launch(void* const* d_in, const int* in_sizes, int n_in,
                              void* d_out, int out_size, void* d_ws,
                              size_t ws_size, hipStream_t stream) {
  (void)in_sizes; (void)n_in; (void)out_size; (void)ws_size;
  const float* x  = (const float*)d_in[0];
  const float* Wq = (const float*)d_in[1];
  const float* bq = (const float*)d_in[2];
  const float* Wk = (const float*)d_in[3];
  const float* bk = (const float*)d_in[4];
  const float* Wv = (const float*)d_in[5];
  const float* bv = (const float*)d_in[6];
  const float* Wo = (const float*)d_in[7];
  const float* bo = (const float*)d_in[8];

  const size_t M = (size_t)BATCH * CSEQ;  // 8192
  char* ws = (char*)d_ws;
  size_t off = 0;
  auto alloc = [&](size_t bytes) {
    char* p = ws + off;
    off += (bytes + 255) & ~(size_t)255;
    return p;
  };
  u16* x_bf   = (u16*)alloc(M * DIM * 2);             // 16 MB (attn aliases)
  u16* Wqkv_t = (u16*)alloc((size_t)NQKV * DIM * 2);  // 6 MB
  u16* Wo_t   = (u16*)alloc((size_t)DIM * DIM * 2);   // 2 MB
  float* bqkv = (float*)alloc(NQKV * 4);              // 12 KB
  u16* QKV    = (u16*)alloc(M * NQKV * 2);            // 48 MB
  u16* Vt     = (u16*)alloc(M * DIM * 2);             // 16 MB
  u16* S      = (u16*)alloc((size_t)BATCH * CSEQ * CSEQ * 2);  // 32 MB
  float* pmax = (float*)alloc((size_t)BATCH * 32 * CSEQ * 4);  // 1 MB
  float* psum = (float*)alloc((size_t)BATCH * 32 * CSEQ * 4);  // 1 MB
  u16* attn   = x_bf;  // x dead after QKV GEMM

  // 1. prep: cast x->bf16 + bias concat + all 4 weight transposes
  prep<<<8192 + 4096, 256, 0, stream>>>((const float4*)x, (ushort4*)x_bf,
                                        Wq, Wk, Wv, Wo, Wqkv_t, Wo_t,
                                        bq, bk, bv, bqkv);

  // 2. fused QKV projection (2-phase): QKV[8192][3072] = x_bf*Wqkv_t^T + bqkv
  gemm_qkv<<<dim3(NQKV / 128, M / 128, 1), 256, 0, stream>>>(
      x_bf, Wqkv_t, QKV, bqkv, DIM, DIM, DIM, NQKV, 0, 0, 0, 1.0f);

  // 3. scores S[b] = Qs[b]*K[b]^T (8-phase, 256 blocks) + per-slice row stats
  gemm8_scores<<<dim3(CSEQ / 256, CSEQ / 256, BATCH), 512, 0, stream>>>(
      QKV, QKV + 1024, S, pmax, psum, DIM, NQKV, NQKV, CSEQ,
      (size_t)CSEQ * NQKV, (size_t)CSEQ * NQKV, (size_t)CSEQ * CSEQ);

  // 4. V transpose out of QKV
  vtrans<<<8192, 256, 0, stream>>>(QKV, Vt);

  // 5. attn[b] = softmax(S[b]) * Vt[b]^T  (2-phase, exp fused in A staging)
  gemm_pv_sm<<<dim3(DIM / 128, CSEQ / 128, BATCH), 256, 0, stream>>>(
      S, Vt, attn, pmax, psum);

  // 6. out = attn * Wo_t^T + bo (fp32 out, 2-phase 128^2)
  gemm_out<<<dim3(DIM / 128, M / 128, 1), 256, 0, stream>>>(
      attn, Wo_t, d_out, bo, DIM, DIM, DIM, DIM, 0, 0, 0, 1.0f);
}